// Round 1
// baseline (707.092 us; speedup 1.0000x reference)
//
#include <hip/hip_runtime.h>
#include <math.h>

#define N_ATOMS 100000
#define B_BB    10000
#define E_EDGES 320000
#define D_DIM   256
#define NHEAD   8
#define HD_DIM  32
#define NDIST   64

#define DELTA   (10.0f/63.0f)
#define GCOEFF  (-0.5f/(DELTA*DELTA))
#define QKSCALE 0.17677669529663687f   /* 1/sqrt(32) */

// ---------------------------------------------------------------------------
// K0: per-bb atom offsets via binary search (bb_vec is sorted); zero edge_cnt
// ---------------------------------------------------------------------------
__global__ void k_offsets(const int* __restrict__ bb_vec, int* __restrict__ atom_off,
                          int* __restrict__ edge_cnt) {
  int b = blockIdx.x * 256 + threadIdx.x;
  if (b <= B_BB) {
    int lo = 0, hi = N_ATOMS;
    while (lo < hi) { int mid = (lo + hi) >> 1; if (bb_vec[mid] < b) lo = mid + 1; else hi = mid; }
    atom_off[b] = lo;
  }
  if (b < B_BB) edge_cnt[b] = 0;
}

// ---------------------------------------------------------------------------
// K1: bb_center_feats (sum) and bb_center_pos (mean). One block per bb.
// ---------------------------------------------------------------------------
__global__ __launch_bounds__(256) void k_bb_centers(
    const float* __restrict__ af, const float* __restrict__ coords,
    const int* __restrict__ atom_off, float* __restrict__ bbF, float* __restrict__ bb_pos) {
  int b = blockIdx.x;
  int s = atom_off[b], e = atom_off[b + 1];
  int t = threadIdx.x;
  float acc = 0.f;
  for (int a = s; a < e; a++) acc += af[(size_t)a * D_DIM + t];
  bbF[(size_t)b * D_DIM + t] = acc;
  if (t < 3) {
    float c = 0.f;
    for (int a = s; a < e; a++) c += coords[(size_t)a * 3 + t];
    float cnt = (float)(e - s);
    bb_pos[b * 4 + t] = c / fmaxf(cnt, 1.0f);
  }
}

// ---------------------------------------------------------------------------
// K2/K9: C[M,256] = A[M,256] @ W[256,256] + bias. 64x64 tile, 4x4 microtile.
// ---------------------------------------------------------------------------
__global__ __launch_bounds__(256) void k_gemm256(
    const float* __restrict__ A, const float* __restrict__ W,
    const float* __restrict__ bias, float* __restrict__ C, int M) {
  __shared__ __align__(16) float As[16][68];
  __shared__ __align__(16) float Ws[16][64];
  int tid = threadIdx.x;
  int tx = tid & 15, ty = tid >> 4;
  int row0 = blockIdx.x * 64, col0 = blockIdx.y * 64;
  float acc[4][4] = {};
  for (int k0 = 0; k0 < 256; k0 += 16) {
    {
      int r = tid >> 2;               // 0..63
      int c = (tid & 3) * 4;          // 0,4,8,12
      int row = row0 + r;
      float4 v = make_float4(0.f, 0.f, 0.f, 0.f);
      if (row < M) v = *(const float4*)&A[(size_t)row * 256 + k0 + c];
      As[c + 0][r] = v.x; As[c + 1][r] = v.y; As[c + 2][r] = v.z; As[c + 3][r] = v.w;
    }
    {
      int r = tid >> 4;               // 0..15
      int c = (tid & 15) * 4;         // 0..60
      float4 v = *(const float4*)&W[(size_t)(k0 + r) * 256 + col0 + c];
      *(float4*)&Ws[r][c] = v;
    }
    __syncthreads();
#pragma unroll
    for (int kk = 0; kk < 16; kk++) {
      float4 a = *(const float4*)&As[kk][ty * 4];
      float4 b = *(const float4*)&Ws[kk][tx * 4];
      float av[4] = {a.x, a.y, a.z, a.w};
      float bv4[4] = {b.x, b.y, b.z, b.w};
#pragma unroll
      for (int i = 0; i < 4; i++)
#pragma unroll
        for (int j = 0; j < 4; j++) acc[i][j] += av[i] * bv4[j];
    }
    __syncthreads();
  }
#pragma unroll
  for (int i = 0; i < 4; i++) {
    int row = row0 + ty * 4 + i;
    if (row < M) {
      int col = col0 + tx * 4;
      float4 r = make_float4(acc[i][0] + bias[col + 0], acc[i][1] + bias[col + 1],
                             acc[i][2] + bias[col + 2], acc[i][3] + bias[col + 3]);
      *(float4*)&C[(size_t)row * 256 + col] = r;
    }
  }
}

// ---------------------------------------------------------------------------
// K3: histogram of tgt
// ---------------------------------------------------------------------------
__global__ void k_hist(const int* __restrict__ tgt, int* __restrict__ edge_cnt) {
  int e = blockIdx.x * 256 + threadIdx.x;
  if (e < E_EDGES) atomicAdd(&edge_cnt[tgt[e]], 1);
}

// ---------------------------------------------------------------------------
// K4: exclusive scan of edge_cnt -> edge_start[B+1], cursor. Single block.
// ---------------------------------------------------------------------------
__global__ __launch_bounds__(1024) void k_scan(
    const int* __restrict__ edge_cnt, int* __restrict__ edge_start, int* __restrict__ cursor) {
  __shared__ int ssum[1024];
  int tid = threadIdx.x;
  int base = tid * 10;
  int v[10]; int s = 0;
#pragma unroll
  for (int k = 0; k < 10; k++) { int i = base + k; v[k] = (i < B_BB) ? edge_cnt[i] : 0; s += v[k]; }
  ssum[tid] = s;
  __syncthreads();
  for (int off = 1; off < 1024; off <<= 1) {
    int t = (tid >= off) ? ssum[tid - off] : 0;
    __syncthreads();
    ssum[tid] += t;
    __syncthreads();
  }
  int excl = ssum[tid] - s;
#pragma unroll
  for (int k = 0; k < 10; k++) {
    int i = base + k;
    if (i < B_BB) { edge_start[i] = excl; cursor[i] = excl; }
    excl += v[k];
  }
  if (tid == 1023) edge_start[B_BB] = E_EDGES;
}

// ---------------------------------------------------------------------------
// K5: CSR fill: src_sorted / dist_sorted in tgt-grouped order
// ---------------------------------------------------------------------------
__global__ void k_fill(const int* __restrict__ src, const int* __restrict__ tgt,
                       const float* __restrict__ coords, const float* __restrict__ bb_pos,
                       int* __restrict__ cursor, int* __restrict__ src_sorted,
                       float* __restrict__ dist_sorted) {
  int e = blockIdx.x * 256 + threadIdx.x;
  if (e >= E_EDGES) return;
  int b = tgt[e], a = src[e];
  int pos = atomicAdd(&cursor[b], 1);
  float dx = coords[a * 3 + 0] - bb_pos[b * 4 + 0];
  float dy = coords[a * 3 + 1] - bb_pos[b * 4 + 1];
  float dz = coords[a * 3 + 2] - bb_pos[b * 4 + 2];
  src_sorted[pos] = a;
  dist_sorted[pos] = sqrtf(dx * dx + dy * dy + dz * dz);
}

// ---------------------------------------------------------------------------
// K6: wt[b,h,i] = scale * sum_c Wk[i, h*32+c] * q[b, h*32+c],  i in [0,320)
// (i<256: atom-feature reduction vector; i>=256: dist-embed reduction vector)
// ---------------------------------------------------------------------------
__global__ __launch_bounds__(256) void k_wt(
    const float* __restrict__ q, const float* __restrict__ Wk, float* __restrict__ wt) {
  __shared__ float Wk_s[320 * 33];
  __shared__ float q_s[32 * 33];
  int h = blockIdx.y;
  int b0 = blockIdx.x * 32;
  int tid = threadIdx.x;
  for (int j = 0; j < 40; j++) {
    int idx = j * 256 + tid;
    int i = idx >> 5, c = idx & 31;
    Wk_s[i * 33 + c] = Wk[(size_t)i * 256 + h * 32 + c];
  }
  for (int j = 0; j < 4; j++) {
    int idx = j * 256 + tid;
    int r = idx >> 5, c = idx & 31;
    int b = b0 + r;
    q_s[r * 33 + c] = (b < B_BB) ? q[(size_t)b * 256 + h * 32 + c] : 0.f;
  }
  __syncthreads();
  for (int j = 0; j < 40; j++) {
    int flat = j * 256 + tid;
    int bb = flat / 320;
    int i = flat - bb * 320;
    int b = b0 + bb;
    float acc = 0.f;
#pragma unroll
    for (int c = 0; c < 32; c++) acc += Wk_s[i * 33 + c] * q_s[bb * 33 + c];
    if (b < B_BB) wt[(size_t)b * 2560 + h * 320 + i] = acc * QKSCALE;
  }
}

// ---------------------------------------------------------------------------
// K7: the hot kernel. One block per bb; each wave owns 2 heads (no barriers
// in the edge loop). Online softmax; accumulates attention-weighted moments:
//   S[h][0:256] = sum_e w_e * af[src_e]   (lane holds 4 dims per head)
//   sd[h][0:64] = sum_e w_e * embed_e     (lane holds 1 dim per head)
// Output (normalized) overwrites wt buffer in-place: Sfull[b,h,0:320].
// ---------------------------------------------------------------------------
__global__ __launch_bounds__(256) void k_attn(
    const float* __restrict__ af, float* __restrict__ wtS,
    const int* __restrict__ edge_start, const int* __restrict__ src_sorted,
    const float* __restrict__ dist_sorted, float* __restrict__ wsum) {
  __shared__ __align__(16) float wts[2560];
  int b = blockIdx.x;
  int tid = threadIdx.x;
  float* wtb = wtS + (size_t)b * 2560;
  for (int i = tid; i < 2560; i += 256) wts[i] = wtb[i];
  __syncthreads();
  int lane = tid & 63;
  int wv = tid >> 6;
  int h0 = 2 * wv, h1 = 2 * wv + 1;
  int s0 = edge_start[b], e1 = edge_start[b + 1];
  float4 S0 = {0.f, 0.f, 0.f, 0.f}, S1 = {0.f, 0.f, 0.f, 0.f};
  float m0 = -1e30f, m1 = -1e30f, l0 = 0.f, l1 = 0.f, sd0 = 0.f, sd1 = 0.f;
  float4 af4n = {0.f, 0.f, 0.f, 0.f};
  float distn = 0.f;
  if (s0 < e1) {
    int a = src_sorted[s0];
    distn = dist_sorted[s0];
    af4n = ((const float4*)(af + (size_t)a * 256))[lane];
  }
  const float* wrow0 = wts + h0 * 320;
  const float* wrow1 = wts + h1 * 320;
  float off_j = lane * DELTA;
  for (int e = s0; e < e1; e++) {
    float4 a4 = af4n;
    float dist = distn;
    if (e + 1 < e1) {                      // 1-deep prefetch; no barriers so
      int a2 = src_sorted[e + 1];          // vmcnt wait lands at next use
      distn = dist_sorted[e + 1];
      af4n = ((const float4*)(af + (size_t)a2 * 256))[lane];
    }
    float dd = dist - off_j;
    float emb = __expf(GCOEFF * dd * dd);
    float4 w0v = *(const float4*)(wrow0 + 4 * lane);
    float4 w1v = *(const float4*)(wrow1 + 4 * lane);
    float p0 = a4.x * w0v.x + a4.y * w0v.y + a4.z * w0v.z + a4.w * w0v.w + emb * wrow0[256 + lane];
    float p1 = a4.x * w1v.x + a4.y * w1v.y + a4.z * w1v.z + a4.w * w1v.w + emb * wrow1[256 + lane];
#pragma unroll
    for (int off = 32; off > 0; off >>= 1) {
      p0 += __shfl_xor(p0, off);
      p1 += __shfl_xor(p1, off);
    }
    float mn0 = fmaxf(m0, p0), mn1 = fmaxf(m1, p1);
    float al0 = __expf(m0 - mn0), al1 = __expf(m1 - mn1);
    float w0 = __expf(p0 - mn0), w1 = __expf(p1 - mn1);
    l0 = l0 * al0 + w0; l1 = l1 * al1 + w1;
    m0 = mn0; m1 = mn1;
    S0.x = S0.x * al0 + w0 * a4.x; S0.y = S0.y * al0 + w0 * a4.y;
    S0.z = S0.z * al0 + w0 * a4.z; S0.w = S0.w * al0 + w0 * a4.w;
    S1.x = S1.x * al1 + w1 * a4.x; S1.y = S1.y * al1 + w1 * a4.y;
    S1.z = S1.z * al1 + w1 * a4.z; S1.w = S1.w * al1 + w1 * a4.w;
    sd0 = sd0 * al0 + w0 * emb; sd1 = sd1 * al1 + w1 * emb;
  }
  float inv0 = 1.0f / (l0 + 1e-16f), inv1 = 1.0f / (l1 + 1e-16f);
  float4 o0 = make_float4(S0.x * inv0, S0.y * inv0, S0.z * inv0, S0.w * inv0);
  float4 o1 = make_float4(S1.x * inv1, S1.y * inv1, S1.z * inv1, S1.w * inv1);
  *(float4*)(wtb + h0 * 320 + 4 * lane) = o0;
  *(float4*)(wtb + h1 * 320 + 4 * lane) = o1;
  wtb[h0 * 320 + 256 + lane] = sd0 * inv0;
  wtb[h1 * 320 + 256 + lane] = sd1 * inv1;
  if (lane == 0) {
    wsum[b * 8 + h0] = l0 * inv0;
    wsum[b * 8 + h1] = l1 * inv1;
  }
}

// ---------------------------------------------------------------------------
// K8: out_pre[b, h*32+c] = sum_i Sfull[b,h,i]*Wv[i, h*32+c] + wsum[b,h]*bv
// ---------------------------------------------------------------------------
__global__ __launch_bounds__(256) void k_out_head(
    const float* __restrict__ Sf, const float* __restrict__ Wv,
    const float* __restrict__ bv, const float* __restrict__ wsum,
    float* __restrict__ out_pre) {
  __shared__ float Wv_s[320 * 32];
  __shared__ float Sf_s[32 * 320];
  int h = blockIdx.y;
  int b0 = blockIdx.x * 32;
  int tid = threadIdx.x;
  for (int j = 0; j < 40; j++) {
    int idx = j * 256 + tid;
    int i = idx >> 5, c = idx & 31;
    Wv_s[idx] = Wv[(size_t)i * 256 + h * 32 + c];
  }
  for (int j = 0; j < 40; j++) {
    int idx = j * 256 + tid;
    int bb = idx / 320;
    int i = idx - bb * 320;
    int b = b0 + bb;
    Sf_s[idx] = (b < B_BB) ? Sf[(size_t)b * 2560 + h * 320 + i] : 0.f;
  }
  __syncthreads();
  int c = tid & 31;
  int bbq = tid >> 5;                       // 0..7
  float acc[4] = {0.f, 0.f, 0.f, 0.f};
  for (int i = 0; i < 320; i++) {
    float w = Wv_s[i * 32 + c];
#pragma unroll
    for (int j = 0; j < 4; j++) acc[j] += Sf_s[(bbq + 8 * j) * 320 + i] * w;
  }
  float bvv = bv[h * 32 + c];
#pragma unroll
  for (int j = 0; j < 4; j++) {
    int b = b0 + bbq + 8 * j;
    if (b < B_BB) out_pre[(size_t)b * 256 + h * 32 + c] = acc[j] + wsum[b * 8 + h] * bvv;
  }
}

// ---------------------------------------------------------------------------
extern "C" void kernel_launch(void* const* d_in, const int* in_sizes, int n_in,
                              void* d_out, int out_size, void* d_ws, size_t ws_size,
                              hipStream_t stream) {
  const float* af     = (const float*)d_in[0];
  const float* coords = (const float*)d_in[1];
  const float* Wq     = (const float*)d_in[2];
  const float* bq     = (const float*)d_in[3];
  const float* Wk     = (const float*)d_in[4];
  const float* bk     = (const float*)d_in[5];  (void)bk; // softmax-invariant, dropped
  const float* Wv     = (const float*)d_in[6];
  const float* bv     = (const float*)d_in[7];
  const float* Wo     = (const float*)d_in[8];
  const float* bo     = (const float*)d_in[9];
  const int* bb_vec   = (const int*)d_in[10];
  const int* src      = (const int*)d_in[11];
  const int* tgt      = (const int*)d_in[12];
  float* out = (float*)d_out;
  (void)in_sizes; (void)n_in; (void)out_size; (void)ws_size;

  char* ws = (char*)d_ws;
  size_t o = 0;
  auto alloc = [&](size_t bytes) { size_t r = o; o += (bytes + 255) & ~(size_t)255; return r; };
  int*   atom_off    = (int*)(ws + alloc((B_BB + 1) * 4));
  int*   edge_cnt    = (int*)(ws + alloc((size_t)B_BB * 4));
  int*   edge_start  = (int*)(ws + alloc((B_BB + 1) * 4));
  int*   cursor      = (int*)(ws + alloc((size_t)B_BB * 4));
  int*   src_sorted  = (int*)(ws + alloc((size_t)E_EDGES * 4));
  float* dist_sorted = (float*)(ws + alloc((size_t)E_EDGES * 4));
  float* bbF         = (float*)(ws + alloc((size_t)B_BB * 256 * 4));
  float* bb_pos      = (float*)(ws + alloc((size_t)B_BB * 4 * 4));
  float* q           = (float*)(ws + alloc((size_t)B_BB * 256 * 4));
  float* wtS         = (float*)(ws + alloc((size_t)B_BB * 2560 * 4)); // wt, then Sfull (in-place)
  float* wsum        = (float*)(ws + alloc((size_t)B_BB * 8 * 4));
  float* out_pre     = (float*)(ws + alloc((size_t)B_BB * 256 * 4));

  k_offsets<<<(B_BB + 1 + 255) / 256, 256, 0, stream>>>(bb_vec, atom_off, edge_cnt);
  k_bb_centers<<<B_BB, 256, 0, stream>>>(af, coords, atom_off, bbF, bb_pos);
  k_hist<<<(E_EDGES + 255) / 256, 256, 0, stream>>>(tgt, edge_cnt);
  k_scan<<<1, 1024, 0, stream>>>(edge_cnt, edge_start, cursor);
  k_fill<<<(E_EDGES + 255) / 256, 256, 0, stream>>>(src, tgt, coords, bb_pos, cursor,
                                                    src_sorted, dist_sorted);
  k_gemm256<<<dim3((B_BB + 63) / 64, 4), 256, 0, stream>>>(bbF, Wq, bq, q, B_BB);
  k_wt<<<dim3((B_BB + 31) / 32, 8), 256, 0, stream>>>(q, Wk, wtS);
  k_attn<<<B_BB, 256, 0, stream>>>(af, wtS, edge_start, src_sorted, dist_sorted, wsum);
  k_out_head<<<dim3((B_BB + 31) / 32, 8), 256, 0, stream>>>(wtS, Wv, bv, wsum, out_pre);
  k_gemm256<<<dim3((B_BB + 63) / 64, 4), 256, 0, stream>>>(out_pre, Wo, bo, out, B_BB);
}